// Round 3
// baseline (981.048 us; speedup 1.0000x reference)
//
#include <hip/hip_runtime.h>
#include <math.h>

#define S     2048
#define D     1024
#define NMEM  32
#define KP    32

__device__ inline float trunc_clip(float v) {
    return truncf(fminf(fmaxf(v, -128.f), 127.f));
}

// ================= K1: entropy (fp64) + column-sum partials, all 33 matrices =================
// grid (NMEM+1)*32 blocks, 256 threads. Block = 64 rows of one matrix (4 waves x 16 rows).
__global__ __launch_bounds__(256)
void k_stats(const float* __restrict__ mem, const float* __restrict__ query,
             float* __restrict__ entropy, float* __restrict__ colsumPart) {
    const int tid = threadIdx.x, wave = tid >> 6, lane = tid & 63;
    const int n    = blockIdx.x >> 5;
    const int tile = blockIdx.x & 31;
    const float* src = (n < NMEM) ? (mem + (size_t)n * S * D) : query;
    const int s0 = tile * 64 + wave * 16;

    __shared__ double redsm[64][33];   // [row][lane-pair], padded to kill bank conflicts
    __shared__ double redsq[64][33];
    __shared__ float  ldscol[D];
    for (int i = tid; i < D; i += 256) ldscol[i] = 0.f;
    __syncthreads();

    float colacc[16];
    #pragma unroll
    for (int i = 0; i < 16; ++i) colacc[i] = 0.f;

    for (int r = 0; r < 16; ++r) {
        const float4* row = (const float4*)(src + (size_t)(s0 + r) * D);
        double sm = 0.0, sq = 0.0;
        #pragma unroll
        for (int it = 0; it < 4; ++it) {
            float4 v = row[it * 64 + lane];
            sm += (double)v.x + (double)v.y + (double)v.z + (double)v.w;
            sq += (double)v.x * v.x + (double)v.y * v.y
                + (double)v.z * v.z + (double)v.w * v.w;
            colacc[it*4+0] += v.x; colacc[it*4+1] += v.y;
            colacc[it*4+2] += v.z; colacc[it*4+3] += v.w;
        }
        // one pair-combine step, then pipelined LDS dump (no serial 6-step chain)
        sm += __shfl_xor(sm, 1, 64);
        sq += __shfl_xor(sq, 1, 64);
        if ((lane & 1) == 0) {
            redsm[wave * 16 + r][lane >> 1] = sm;
            redsq[wave * 16 + r][lane >> 1] = sq;
        }
    }
    // column sums into LDS (block-level, no global atomics)
    #pragma unroll
    for (int it = 0; it < 4; ++it)
        #pragma unroll
        for (int j = 0; j < 4; ++j)
            atomicAdd(&ldscol[it*256 + lane*4 + j], colacc[it*4+j]);
    __syncthreads();

    // phase 2: finish row reductions (4 threads per row)
    if (n < NMEM) {
        const int row = tid >> 2, qq = tid & 3;
        double sm = 0.0, sq = 0.0;
        #pragma unroll
        for (int i = 0; i < 8; ++i) { sm += redsm[row][qq*8 + i]; sq += redsq[row][qq*8 + i]; }
        sm += __shfl_xor(sm, 1, 64); sq += __shfl_xor(sq, 1, 64);
        sm += __shfl_xor(sm, 2, 64); sq += __shfl_xor(sq, 2, 64);
        if (qq == 0) {
            double var = (sq - sm * sm / (double)D) / (double)(D - 1);
            entropy[(size_t)n * S + tile * 64 + row] = (float)sqrt(var > 0.0 ? var : 0.0);
        }
    }
    for (int i = tid; i < D; i += 256)
        colsumPart[((size_t)n * 32 + tile) * D + i] = ldscol[i];
}

// ================= K2: rank-count selection (top-32 rows) + column-mean reduce =================
// grid NMEM+1 blocks, 1024 threads. Block 32 = query (colmean only).
__global__ __launch_bounds__(1024)
void k_select(const float* __restrict__ entropy, const float* __restrict__ colsumPart,
              int* __restrict__ idxSel, float* __restrict__ feats) {
    const int n = blockIdx.x, tid = threadIdx.x;
    {   // column mean for meta features
        float acc = 0.f;
        #pragma unroll 4
        for (int t = 0; t < 32; ++t) acc += colsumPart[((size_t)n * 32 + t) * D + tid];
        feats[(size_t)n * D + tid] = acc * (1.f / (float)S);
    }
    if (n >= NMEM) return;

    __shared__ unsigned long long key[S];
    const float* e = entropy + (size_t)n * S;
    for (int i = tid; i < S; i += 1024) {
        unsigned int b = __float_as_uint(e[i]);   // e >= 0: bits are order-preserving
        key[i] = ((unsigned long long)b << 32) | (unsigned long long)(S - 1 - i);
    }
    __syncthreads();
    const unsigned long long k0 = key[tid], k1 = key[tid + 1024];
    int c0 = 0, c1 = 0;
    for (int j = 0; j < S; j += 4) {
        unsigned long long a0 = key[j], a1 = key[j+1], a2 = key[j+2], a3 = key[j+3];
        c0 += (a0 > k0) + (a1 > k0) + (a2 > k0) + (a3 > k0);
        c1 += (a0 > k1) + (a1 > k1) + (a2 > k1) + (a3 > k1);
    }
    if (c0 < KP) idxSel[n * KP + c0] = tid;
    if (c1 < KP) idxSel[n * KP + c1] = tid + 1024;
}

// ================= K3: aggregate rows (gather form) + row entropy of aggregate =================
// grid S blocks, 256 threads. Block = one row s.
__global__ __launch_bounds__(256)
void k_aggregate(const float* __restrict__ mem, const float* __restrict__ query,
                 const int* __restrict__ idxSel, float* __restrict__ agg,
                 float* __restrict__ entAgg) {
    const int s = blockIdx.x, tid = threadIdx.x;
    __shared__ int    sidx[NMEM * KP];
    __shared__ int    sel_n[NMEM];
    __shared__ int    selCount;
    __shared__ double rsm[256], rsq[256];
    __shared__ double fsm[64],  fsq[64];
    if (tid == 0) selCount = 0;
    for (int i = tid; i < NMEM * KP; i += 256) sidx[i] = idxSel[i];
    __syncthreads();
    #pragma unroll
    for (int k = 0; k < 4; ++k) {
        int e = tid * 4 + k;
        if (sidx[e] == s) { int p = atomicAdd(&selCount, 1); sel_n[p] = e >> 5; }
    }
    __syncthreads();

    float4 acc = ((const float4*)(query + (size_t)s * D))[tid];
    const int cnt = selCount;
    for (int c = 0; c < cnt; ++c) {
        const int n = sel_n[c];
        float4 v = ((const float4*)(mem + ((size_t)n * S + s) * D))[tid];
        acc.x += trunc_clip(v.x); acc.y += trunc_clip(v.y);
        acc.z += trunc_clip(v.z); acc.w += trunc_clip(v.w);
    }
    const float sc = 1.f / 33.f;
    acc.x *= sc; acc.y *= sc; acc.z *= sc; acc.w *= sc;
    ((float4*)(agg + (size_t)s * D))[tid] = acc;

    double sm = (double)acc.x + (double)acc.y + (double)acc.z + (double)acc.w;
    double sq = (double)acc.x * acc.x + (double)acc.y * acc.y
              + (double)acc.z * acc.z + (double)acc.w * acc.w;
    rsm[tid] = sm; rsq[tid] = sq;
    __syncthreads();
    if (tid < 64) {
        double a = 0, b = 0;
        #pragma unroll
        for (int i = 0; i < 4; ++i) { a += rsm[tid + 64*i]; b += rsq[tid + 64*i]; }
        fsm[tid] = a; fsq[tid] = b;
    }
    __syncthreads();
    if (tid == 0) {
        double a = 0, b = 0;
        for (int i = 0; i < 64; ++i) { a += fsm[i]; b += fsq[i]; }
        double var = (b - a * a / (double)D) / (double)(D - 1);
        entAgg[s] = (float)sqrt(var > 0.0 ? var : 0.0);
    }
}

// ================= K4: reconstruction output with inline rank test =================
// grid S blocks, 256 threads. Block = one output row.
__global__ __launch_bounds__(256)
void k_recon(const float* __restrict__ agg, const float* __restrict__ entAgg,
             float* __restrict__ outRecon) {
    const int s = blockIdx.x, tid = threadIdx.x;
    __shared__ float ent[S];
    __shared__ int   cnts[256];
    __shared__ int   rankS;
    for (int i = tid; i < S; i += 256) ent[i] = entAgg[i];
    __syncthreads();
    const float es = ent[s];
    int c = 0;
    for (int i = tid; i < S; i += 256) {
        float ej = ent[i];
        c += (ej > es) || (ej == es && i < s);
    }
    cnts[tid] = c;
    __syncthreads();
    if (tid < 32) {
        int a = 0;
        #pragma unroll
        for (int i = 0; i < 8; ++i) a += cnts[tid + 32 * i];
        cnts[tid] = a;
    }
    __syncthreads();
    if (tid == 0) {
        int r = 0;
        for (int i = 0; i < 32; ++i) r += cnts[i];
        rankS = r;
    }
    __syncthreads();
    float4 o = make_float4(0.f, 0.f, 0.f, 0.f);
    if (rankS < KP) {
        float4 v = ((const float4*)(agg + (size_t)s * D))[tid];
        o.x = trunc_clip(v.x); o.y = trunc_clip(v.y);
        o.z = trunc_clip(v.z); o.w = trunc_clip(v.w);
    }
    ((float4*)(outRecon + (size_t)s * D))[tid] = o;
}

// ================= K5: fused scheduler (mlp1 + mlp2 + cosine sims + ranking) =================
// 1 block, 1024 threads.
__global__ __launch_bounds__(1024)
void k_sched(const float* __restrict__ feats, const float* __restrict__ surprise,
             const float* __restrict__ priority,
             const float* __restrict__ W1, const float* __restrict__ b1,
             const float* __restrict__ W2, const float* __restrict__ b2,
             float* __restrict__ outSims, float* __restrict__ outIdx) {
    const int tid = threadIdx.x;
    __shared__ float sfeat[33 * 64];
    __shared__ float lhid[33 * 128];
    __shared__ float lss[16 * 33], ldt[16 * 33];
    __shared__ float simsS[NMEM];

    // ---- layer 1: hidden[33][128] ----
    const int h = tid & 127, mg = tid >> 7;           // 8 thread-groups over h
    float acc[5];
    #pragma unroll
    for (int i = 0; i < 5; ++i) acc[i] = b1[h];
    for (int jt = 0; jt < 16; ++jt) {
        for (int i = tid; i < 33 * 64; i += 1024) {
            int m = i >> 6, j = i & 63;
            sfeat[i] = feats[(size_t)m * D + jt * 64 + j];
        }
        __syncthreads();
        for (int j = 0; j < 64; ++j) {
            float w = W1[(size_t)(jt * 64 + j) * 128 + h];
            #pragma unroll
            for (int i = 0; i < 5; ++i) {
                int m = mg + i * 8;
                if (m < 33) acc[i] += sfeat[m * 64 + j] * w;
            }
        }
        __syncthreads();
    }
    {   // feature j=1024 = surprise (j=1025/1026 are zeros)
        float w = W1[(size_t)D * 128 + h];
        #pragma unroll
        for (int i = 0; i < 5; ++i) {
            int m = mg + i * 8;
            if (m < NMEM) acc[i] += surprise[m] * w;
        }
    }
    #pragma unroll
    for (int i = 0; i < 5; ++i) {
        int m = mg + i * 8;
        if (m < 33) lhid[m * 128 + h] = fmaxf(acc[i], 0.f);
    }
    __syncthreads();

    // ---- layer 2: thread owns column d; accumulate all 33 embeddings ----
    const int d = tid;
    float a2[33];
    #pragma unroll
    for (int m = 0; m < 33; ++m) a2[m] = b2[d];
    for (int k = 0; k < 128; ++k) {
        float w = W2[(size_t)k * D + d];
        #pragma unroll
        for (int m = 0; m < 33; ++m) a2[m] += lhid[m * 128 + k] * w;
    }

    // ---- norms and dots ----
    const int lane = tid & 63, wv = tid >> 6;
    const float qv = a2[32];
    for (int m = 0; m < 33; ++m) {
        float ss = a2[m] * a2[m];
        float dt = a2[m] * qv;
        #pragma unroll
        for (int off = 32; off > 0; off >>= 1) {
            ss += __shfl_xor(ss, off, 64);
            dt += __shfl_xor(dt, off, 64);
        }
        if (lane == 0) { lss[wv * 33 + m] = ss; ldt[wv * 33 + m] = dt; }
    }
    __syncthreads();
    if (tid < 33) {
        float ss = 0.f, dt = 0.f;
        for (int w = 0; w < 16; ++w) { ss += lss[w * 33 + tid]; dt += ldt[w * 33 + tid]; }
        lss[tid] = ss; ldt[tid] = dt;
    }
    __syncthreads();
    if (tid < NMEM) {
        float qn = fmaxf(sqrtf(lss[32]),  1e-8f);
        float mn = fmaxf(sqrtf(lss[tid]), 1e-8f);
        float sv = ldt[tid] / (mn * qn) * priority[tid];
        simsS[tid] = sv;
        outSims[tid] = sv;
    }
    __syncthreads();
    if (tid < NMEM) {
        float si = simsS[tid];
        int r = 0;
        #pragma unroll
        for (int j = 0; j < NMEM; ++j) {
            float sj = simsS[j];
            r += (sj > si) || (sj == si && j < tid);
        }
        outIdx[r] = (float)tid;
    }
}

extern "C" void kernel_launch(void* const* d_in, const int* in_sizes, int n_in,
                              void* d_out, int out_size, void* d_ws, size_t ws_size,
                              hipStream_t stream) {
    const float* query    = (const float*)d_in[0];
    const float* memories = (const float*)d_in[1];
    const float* surprise = (const float*)d_in[2];
    const float* priority = (const float*)d_in[3];
    const float* W1 = (const float*)d_in[4];
    const float* b1 = (const float*)d_in[5];
    const float* W2 = (const float*)d_in[6];
    const float* b2 = (const float*)d_in[7];
    float* out = (float*)d_out;
    char*  ws  = (char*)d_ws;

    // ws layout (bytes)
    float* entropy    = (float*)(ws + 0);          // 32*2048*4      = 262144
    float* colsumPart = (float*)(ws + 262144);     // 33*32*1024*4   = 4325376
    float* feats      = (float*)(ws + 4587520);    // 33*1024*4      = 135168
    int*   idxSel     = (int*)  (ws + 4722688);    // 1024*4         = 4096
    float* agg        = (float*)(ws + 4726784);    // 2048*1024*4    = 8388608
    float* entAgg     = (float*)(ws + 13115392);   // 2048*4         = 8192

    float* outSims   = out + (size_t)S * D;
    float* outTopIdx = outSims + NMEM;

    k_stats    <<<(NMEM + 1) * 32, 256,  0, stream>>>(memories, query, entropy, colsumPart);
    k_select   <<<NMEM + 1,        1024, 0, stream>>>(entropy, colsumPart, idxSel, feats);
    k_aggregate<<<S,               256,  0, stream>>>(memories, query, idxSel, agg, entAgg);
    k_recon    <<<S,               256,  0, stream>>>(agg, entAgg, out);
    k_sched    <<<1,               1024, 0, stream>>>(feats, surprise, priority,
                                                      W1, b1, W2, b2, outSims, outTopIdx);
}

// Round 4
// 524.671 us; speedup vs baseline: 1.8698x; 1.8698x over previous
//
#include <hip/hip_runtime.h>
#include <math.h>

#define S     2048
#define D     1024
#define NMEM  32
#define KP    32

__device__ inline float trunc_clip(float v) {
    return truncf(fminf(fmaxf(v, -128.f), 127.f));
}

// ================= K1: entropy (fp64) + column-sum partials, all 33 matrices =================
// grid (NMEM+1)*32 blocks, 256 threads. Block = 64 rows of one matrix (4 waves x 16 rows).
__global__ __launch_bounds__(256)
void k_stats(const float* __restrict__ mem, const float* __restrict__ query,
             float* __restrict__ entropy, float* __restrict__ colsumPart) {
    const int tid = threadIdx.x, wave = tid >> 6, lane = tid & 63;
    const int n    = blockIdx.x >> 5;
    const int tile = blockIdx.x & 31;
    const float* src = (n < NMEM) ? (mem + (size_t)n * S * D) : query;
    const int s0 = tile * 64 + wave * 16;

    __shared__ double redsm[64][33];   // [row][lane-pair], padded to kill bank conflicts
    __shared__ double redsq[64][33];
    __shared__ float  ldscol[D];
    for (int i = tid; i < D; i += 256) ldscol[i] = 0.f;
    __syncthreads();

    float colacc[16];
    #pragma unroll
    for (int i = 0; i < 16; ++i) colacc[i] = 0.f;

    for (int r = 0; r < 16; ++r) {
        const float4* row = (const float4*)(src + (size_t)(s0 + r) * D);
        double sm = 0.0, sq = 0.0;
        #pragma unroll
        for (int it = 0; it < 4; ++it) {
            float4 v = row[it * 64 + lane];
            sm += (double)v.x + (double)v.y + (double)v.z + (double)v.w;
            sq += (double)v.x * v.x + (double)v.y * v.y
                + (double)v.z * v.z + (double)v.w * v.w;
            colacc[it*4+0] += v.x; colacc[it*4+1] += v.y;
            colacc[it*4+2] += v.z; colacc[it*4+3] += v.w;
        }
        // one pair-combine step, then pipelined LDS dump (no serial 6-step chain)
        sm += __shfl_xor(sm, 1, 64);
        sq += __shfl_xor(sq, 1, 64);
        if ((lane & 1) == 0) {
            redsm[wave * 16 + r][lane >> 1] = sm;
            redsq[wave * 16 + r][lane >> 1] = sq;
        }
    }
    // column sums into LDS (block-level, no global atomics)
    #pragma unroll
    for (int it = 0; it < 4; ++it)
        #pragma unroll
        for (int j = 0; j < 4; ++j)
            atomicAdd(&ldscol[it*256 + lane*4 + j], colacc[it*4+j]);
    __syncthreads();

    // phase 2: finish row reductions (4 threads per row)
    if (n < NMEM) {
        const int row = tid >> 2, qq = tid & 3;
        double sm = 0.0, sq = 0.0;
        #pragma unroll
        for (int i = 0; i < 8; ++i) { sm += redsm[row][qq*8 + i]; sq += redsq[row][qq*8 + i]; }
        sm += __shfl_xor(sm, 1, 64); sq += __shfl_xor(sq, 1, 64);
        sm += __shfl_xor(sm, 2, 64); sq += __shfl_xor(sq, 2, 64);
        if (qq == 0) {
            double var = (sq - sm * sm / (double)D) / (double)(D - 1);
            entropy[(size_t)n * S + tile * 64 + row] = (float)sqrt(var > 0.0 ? var : 0.0);
        }
    }
    for (int i = tid; i < D; i += 256)
        colsumPart[((size_t)n * 32 + tile) * D + i] = ldscol[i];
}

// ================= K2: rank-count selection (top-32 rows) + column-mean reduce =================
// grid NMEM+1 blocks, 1024 threads. Block 32 = query (colmean only).
__global__ __launch_bounds__(1024)
void k_select(const float* __restrict__ entropy, const float* __restrict__ colsumPart,
              int* __restrict__ idxSel, float* __restrict__ feats) {
    const int n = blockIdx.x, tid = threadIdx.x;
    {   // column mean for meta features
        float acc = 0.f;
        #pragma unroll 4
        for (int t = 0; t < 32; ++t) acc += colsumPart[((size_t)n * 32 + t) * D + tid];
        feats[(size_t)n * D + tid] = acc * (1.f / (float)S);
    }
    if (n >= NMEM) return;

    __shared__ unsigned long long key[S];
    const float* e = entropy + (size_t)n * S;
    for (int i = tid; i < S; i += 1024) {
        unsigned int b = __float_as_uint(e[i]);   // e >= 0: bits are order-preserving
        key[i] = ((unsigned long long)b << 32) | (unsigned long long)(S - 1 - i);
    }
    __syncthreads();
    const unsigned long long k0 = key[tid], k1 = key[tid + 1024];
    int c0 = 0, c1 = 0;
    for (int j = 0; j < S; j += 4) {
        unsigned long long a0 = key[j], a1 = key[j+1], a2 = key[j+2], a3 = key[j+3];
        c0 += (a0 > k0) + (a1 > k0) + (a2 > k0) + (a3 > k0);
        c1 += (a0 > k1) + (a1 > k1) + (a2 > k1) + (a3 > k1);
    }
    if (c0 < KP) idxSel[n * KP + c0] = tid;
    if (c1 < KP) idxSel[n * KP + c1] = tid + 1024;
}

// ================= K3: aggregate rows (gather form) + row entropy of aggregate =================
// grid S blocks, 256 threads. Block = one row s.
__global__ __launch_bounds__(256)
void k_aggregate(const float* __restrict__ mem, const float* __restrict__ query,
                 const int* __restrict__ idxSel, float* __restrict__ agg,
                 float* __restrict__ entAgg) {
    const int s = blockIdx.x, tid = threadIdx.x;
    __shared__ int    sidx[NMEM * KP];
    __shared__ int    sel_n[NMEM];
    __shared__ int    selCount;
    __shared__ double rsm[256], rsq[256];
    __shared__ double fsm[64],  fsq[64];
    if (tid == 0) selCount = 0;
    for (int i = tid; i < NMEM * KP; i += 256) sidx[i] = idxSel[i];
    __syncthreads();
    #pragma unroll
    for (int k = 0; k < 4; ++k) {
        int e = tid * 4 + k;
        if (sidx[e] == s) { int p = atomicAdd(&selCount, 1); sel_n[p] = e >> 5; }
    }
    __syncthreads();

    float4 acc = ((const float4*)(query + (size_t)s * D))[tid];
    const int cnt = selCount;
    for (int c = 0; c < cnt; ++c) {
        const int n = sel_n[c];
        float4 v = ((const float4*)(mem + ((size_t)n * S + s) * D))[tid];
        acc.x += trunc_clip(v.x); acc.y += trunc_clip(v.y);
        acc.z += trunc_clip(v.z); acc.w += trunc_clip(v.w);
    }
    const float sc = 1.f / 33.f;
    acc.x *= sc; acc.y *= sc; acc.z *= sc; acc.w *= sc;
    ((float4*)(agg + (size_t)s * D))[tid] = acc;

    double sm = (double)acc.x + (double)acc.y + (double)acc.z + (double)acc.w;
    double sq = (double)acc.x * acc.x + (double)acc.y * acc.y
              + (double)acc.z * acc.z + (double)acc.w * acc.w;
    rsm[tid] = sm; rsq[tid] = sq;
    __syncthreads();
    if (tid < 64) {
        double a = 0, b = 0;
        #pragma unroll
        for (int i = 0; i < 4; ++i) { a += rsm[tid + 64*i]; b += rsq[tid + 64*i]; }
        fsm[tid] = a; fsq[tid] = b;
    }
    __syncthreads();
    if (tid == 0) {
        double a = 0, b = 0;
        for (int i = 0; i < 64; ++i) { a += fsm[i]; b += fsq[i]; }
        double var = (b - a * a / (double)D) / (double)(D - 1);
        entAgg[s] = (float)sqrt(var > 0.0 ? var : 0.0);
    }
}

// ================= K4: reconstruction output with inline rank test =================
// grid S blocks, 256 threads. Block = one output row.
__global__ __launch_bounds__(256)
void k_recon(const float* __restrict__ agg, const float* __restrict__ entAgg,
             float* __restrict__ outRecon) {
    const int s = blockIdx.x, tid = threadIdx.x;
    __shared__ float ent[S];
    __shared__ int   cnts[256];
    __shared__ int   rankS;
    for (int i = tid; i < S; i += 256) ent[i] = entAgg[i];
    __syncthreads();
    const float es = ent[s];
    int c = 0;
    for (int i = tid; i < S; i += 256) {
        float ej = ent[i];
        c += (ej > es) || (ej == es && i < s);
    }
    cnts[tid] = c;
    __syncthreads();
    if (tid < 32) {
        int a = 0;
        #pragma unroll
        for (int i = 0; i < 8; ++i) a += cnts[tid + 32 * i];
        cnts[tid] = a;
    }
    __syncthreads();
    if (tid == 0) {
        int r = 0;
        for (int i = 0; i < 32; ++i) r += cnts[i];
        rankS = r;
    }
    __syncthreads();
    float4 o = make_float4(0.f, 0.f, 0.f, 0.f);
    if (rankS < KP) {
        float4 v = ((const float4*)(agg + (size_t)s * D))[tid];
        o.x = trunc_clip(v.x); o.y = trunc_clip(v.y);
        o.z = trunc_clip(v.z); o.w = trunc_clip(v.w);
    }
    ((float4*)(outRecon + (size_t)s * D))[tid] = o;
}

// ================= K5: MLP layer 1 =================
// grid NMEM+1 blocks, 256 threads. Block m: hidden[m][h] = relu(b1[h] + feats[m] @ W1)
__global__ __launch_bounds__(256)
void k_mlp1(const float* __restrict__ feats, const float* __restrict__ surprise,
            const float* __restrict__ W1, const float* __restrict__ b1,
            float* __restrict__ hidden) {
    const int m = blockIdx.x, tid = threadIdx.x;
    const int h = tid & 127, half = tid >> 7;     // 2 j-halves of 512 each
    __shared__ float lf[D];
    __shared__ float part[256];
    for (int i = tid; i < D; i += 256) lf[i] = feats[(size_t)m * D + i];
    __syncthreads();
    const int j0 = half * 512;
    float a0 = 0.f, a1 = 0.f, a2 = 0.f, a3 = 0.f;
    for (int j = 0; j < 512; j += 4) {
        a0 += lf[j0 + j + 0] * W1[(size_t)(j0 + j + 0) * 128 + h];
        a1 += lf[j0 + j + 1] * W1[(size_t)(j0 + j + 1) * 128 + h];
        a2 += lf[j0 + j + 2] * W1[(size_t)(j0 + j + 2) * 128 + h];
        a3 += lf[j0 + j + 3] * W1[(size_t)(j0 + j + 3) * 128 + h];
    }
    part[tid] = (a0 + a1) + (a2 + a3);
    __syncthreads();
    if (half == 0) {
        float acc = b1[h] + part[h] + part[128 + h];
        if (m < NMEM) acc += surprise[m] * W1[(size_t)D * 128 + h];  // j=1024; 1025/1026 zero
        hidden[(size_t)m * 128 + h] = fmaxf(acc, 0.f);
    }
}

// ================= K6: MLP layer 2 =================
// grid NMEM+1 blocks, 256 threads. Block m: emb[m][d] = b2[d] + hidden[m] @ W2
__global__ __launch_bounds__(256)
void k_mlp2(const float* __restrict__ hidden, const float* __restrict__ W2,
            const float* __restrict__ b2, float* __restrict__ emb) {
    const int m = blockIdx.x, tid = threadIdx.x;
    __shared__ float lh[128];
    if (tid < 128) lh[tid] = hidden[(size_t)m * 128 + tid];
    __syncthreads();
    const int d0 = tid, d1 = tid + 256, d2 = tid + 512, d3 = tid + 768;
    float a0 = b2[d0], a1 = b2[d1], a2 = b2[d2], a3 = b2[d3];
    for (int k = 0; k < 128; ++k) {
        const float hk = lh[k];
        const float* wr = W2 + (size_t)k * D;
        a0 += hk * wr[d0]; a1 += hk * wr[d1];
        a2 += hk * wr[d2]; a3 += hk * wr[d3];
    }
    float* er = emb + (size_t)m * D;
    er[d0] = a0; er[d1] = a1; er[d2] = a2; er[d3] = a3;
}

// ================= K7: per-row ||emb||^2 and dot with q_emb =================
__global__ __launch_bounds__(256)
void k_simsdot(const float* __restrict__ emb, float* __restrict__ ssq,
               float* __restrict__ dotv) {
    const int m = blockIdx.x;
    const int tid = threadIdx.x, wave = tid >> 6, lane = tid & 63;
    float4 v = ((const float4*)(emb + (size_t)m * D))[tid];
    float4 q = ((const float4*)(emb + (size_t)NMEM * D))[tid];
    double ss = (double)v.x * v.x + (double)v.y * v.y
              + (double)v.z * v.z + (double)v.w * v.w;
    double dt = (double)v.x * q.x + (double)v.y * q.y
              + (double)v.z * q.z + (double)v.w * q.w;
    #pragma unroll
    for (int off = 32; off > 0; off >>= 1) {
        ss += __shfl_xor(ss, off, 64);
        dt += __shfl_xor(dt, off, 64);
    }
    __shared__ double wss[4], wdt[4];
    if (lane == 0) { wss[wave] = ss; wdt[wave] = dt; }
    __syncthreads();
    if (tid == 0) {
        double a = 0, b = 0;
        #pragma unroll
        for (int w = 0; w < 4; ++w) { a += wss[w]; b += wdt[w]; }
        ssq[m] = (float)a;
        if (m < NMEM) dotv[m] = (float)b;
    }
}

// ================= K8: final sims + stable descending rank -> top_idx =================
__global__ __launch_bounds__(64)
void k_final(const float* __restrict__ ssq, const float* __restrict__ dotv,
             const float* __restrict__ prio, float* __restrict__ outSims,
             float* __restrict__ outIdx) {
    __shared__ float sims[NMEM];
    const int t = threadIdx.x;
    const float qn = fmaxf(sqrtf(ssq[NMEM]), 1e-8f);
    if (t < NMEM) {
        const float mn = fmaxf(sqrtf(ssq[t]), 1e-8f);
        const float sv = dotv[t] / (mn * qn) * prio[t];
        sims[t] = sv;
        outSims[t] = sv;
    }
    __syncthreads();
    if (t < NMEM) {
        const float si = sims[t];
        int rank = 0;
        #pragma unroll
        for (int j = 0; j < NMEM; ++j) {
            const float sj = sims[j];
            rank += (sj > si) || (sj == si && j < t);
        }
        outIdx[rank] = (float)t;
    }
}

extern "C" void kernel_launch(void* const* d_in, const int* in_sizes, int n_in,
                              void* d_out, int out_size, void* d_ws, size_t ws_size,
                              hipStream_t stream) {
    const float* query    = (const float*)d_in[0];
    const float* memories = (const float*)d_in[1];
    const float* surprise = (const float*)d_in[2];
    const float* priority = (const float*)d_in[3];
    const float* W1 = (const float*)d_in[4];
    const float* b1 = (const float*)d_in[5];
    const float* W2 = (const float*)d_in[6];
    const float* b2 = (const float*)d_in[7];
    float* out = (float*)d_out;
    char*  ws  = (char*)d_ws;

    // ws layout (bytes)
    float* entropy    = (float*)(ws + 0);          // 262144
    float* colsumPart = (float*)(ws + 262144);     // 4325376
    float* feats      = (float*)(ws + 4587520);    // 135168
    int*   idxSel     = (int*)  (ws + 4722688);    // 4096
    float* agg        = (float*)(ws + 4726784);    // 8388608
    float* entAgg     = (float*)(ws + 13115392);   // 8192
    float* hidden     = (float*)(ws + 13123584);   // 16896
    float* emb        = (float*)(ws + 13140480);   // 135168
    float* ssq        = (float*)(ws + 13275648);   // 256
    float* dotv       = (float*)(ws + 13275904);   // 256

    float* outSims   = out + (size_t)S * D;
    float* outTopIdx = outSims + NMEM;

    k_stats    <<<(NMEM + 1) * 32, 256,  0, stream>>>(memories, query, entropy, colsumPart);
    k_select   <<<NMEM + 1,        1024, 0, stream>>>(entropy, colsumPart, idxSel, feats);
    k_aggregate<<<S,               256,  0, stream>>>(memories, query, idxSel, agg, entAgg);
    k_recon    <<<S,               256,  0, stream>>>(agg, entAgg, out);
    k_mlp1     <<<NMEM + 1,        256,  0, stream>>>(feats, surprise, W1, b1, hidden);
    k_mlp2     <<<NMEM + 1,        256,  0, stream>>>(hidden, W2, b2, emb);
    k_simsdot  <<<NMEM + 1,        256,  0, stream>>>(emb, ssq, dotv);
    k_final    <<<1,               64,   0, stream>>>(ssq, dotv, priority, outSims, outTopIdx);
}